// Round 3
// baseline (1433.949 us; speedup 1.0000x reference)
//
#include <hip/hip_runtime.h>
#include <hip/hip_bf16.h>

#define DIM 128
#define N_SEG 100000

typedef __attribute__((ext_vector_type(8))) __bf16 bf16x8;
typedef __attribute__((ext_vector_type(4))) float f32x4;

// ---- d_ws layout (u32 element offsets) -------------------------------------
// [0]        flag (idx width probe)
// [64]       off[N_SEG+1]  — histogram, then exclusive offsets (scan in place)
// [WS_RUN]   run[N_SEG]    — running cursors for rank-scatter
// [WS_ORDER] order[1.6M]   — row ids grouped by segment
// total = 200066 + 1600000 u32 = 7.2 MB
#define WS_OFF 64
#define WS_RUN (WS_OFF + N_SEG + 2)
#define WS_ORDER (WS_RUN + N_SEG)

// ---------------------------------------------------------------------------
// Probe: int64 index => every odd 32-bit word is 0. flag=1 => int32 layout.
// ---------------------------------------------------------------------------
__global__ void idx_probe_kernel(const unsigned* __restrict__ idx32,
                                 unsigned* __restrict__ flag, int n) {
  unsigned v = 0;
  const int stride = gridDim.x * blockDim.x;
  for (int i = blockIdx.x * blockDim.x + threadIdx.x; i < n; i += stride)
    v |= idx32[2 * i + 1];
  if (v) atomicOr(flag, 1u);
}

__global__ void hist_kernel(const int* __restrict__ idx,
                            const unsigned* __restrict__ flag,
                            unsigned* __restrict__ cnt, int n) {
  const bool idx64 = (*flag == 0u);
  const int stride = gridDim.x * blockDim.x;
  for (int i = blockIdx.x * blockDim.x + threadIdx.x; i < n; i += stride) {
    const int v = idx64 ? idx[2 * i] : idx[i];
    atomicAdd(&cnt[v], 1u);
  }
}

// Single-block exclusive scan over N_SEG+1 counters (in place) + copy to run[].
#define SCAN_T 1024
#define SCAN_CHUNK 98  // 1024*98 = 100352 >= 100001
__global__ __launch_bounds__(1024) void scan_kernel(unsigned* __restrict__ off,
                                                    unsigned* __restrict__ run) {
  __shared__ unsigned part[SCAN_T];
  const int t = threadIdx.x;
  const int lo = t * SCAN_CHUNK;
  const int hi = min(lo + SCAN_CHUNK, N_SEG + 1);
  unsigned s = 0;
  for (int i = lo; i < hi; ++i) s += off[i];
  part[t] = s;
  __syncthreads();
  for (int d = 1; d < SCAN_T; d <<= 1) {
    const unsigned v = (t >= d) ? part[t - d] : 0u;
    __syncthreads();
    part[t] += v;
    __syncthreads();
  }
  unsigned running = (t == 0) ? 0u : part[t - 1];
  for (int i = lo; i < hi; ++i) {
    const unsigned v = off[i];
    off[i] = running;
    if (i < N_SEG) run[i] = running;
    running += v;
  }
}

__global__ void rank_kernel(const int* __restrict__ idx,
                            const unsigned* __restrict__ flag,
                            unsigned* __restrict__ run,
                            unsigned* __restrict__ order, int n) {
  const bool idx64 = (*flag == 0u);
  const int stride = gridDim.x * blockDim.x;
  for (int i = blockIdx.x * blockDim.x + threadIdx.x; i < n; i += stride) {
    const int v = idx64 ? idx[2 * i] : idx[i];
    const unsigned pos = atomicAdd(&run[v], 1u);
    order[pos] = (unsigned)i;
  }
}

// ---------------------------------------------------------------------------
// Main: one wave per segment. Gather the segment's e-rows (grouped via
// order[]) in 16-row chunks, h = relu(e@W^T + b) via MFMA, accumulate column
// sums in registers across chunks, cross-lane reduce, ONE plain store per
// output row. Zero atomics on out.
//
// Fragment layouts (mfma_f32_16x16x32_bf16, m89-verified):
//   A (lane l, elem j): e[row_{l&15}][32t + (l>>4)*8 + j]
//   B (lane l, elem j): W[k0*16 + (l&15)][32t + (l>>4)*8 + j]   (LDS frags)
//   C/D (lane l, reg r): h[chunk row (l>>4)*4 + r][k0*16 + (l&15)]
// ---------------------------------------------------------------------------
__global__ __launch_bounds__(256, 4) void fused_main(
    const float* __restrict__ e, const float* __restrict__ W,
    const float* __restrict__ bias_p, const unsigned* __restrict__ off,
    const unsigned* __restrict__ order, float* __restrict__ out) {
  __shared__ bf16x8 wlds[2048];  // 32 KiB: [k0][t][lane] fragment-major

  const int tid = threadIdx.x;
  const int wave = tid >> 6;
  const int lane = tid & 63;
  const int lr = lane & 15;
  const int lg = lane >> 4;

  // one-time: stage W as bf16 fragments into LDS (verified in round 2)
#pragma unroll
  for (int j = 0; j < 8; ++j) {
    const int g = (tid << 3) | j;
    const int gl = g & 63;
    const int tt = (g >> 6) & 3;
    const int k0 = g >> 8;
    const int row = k0 * 16 + (gl & 15);
    const int col = tt * 32 + (gl >> 4) * 8;
    const float* src = W + (size_t)row * DIM + col;
    f32x4 w0 = *(const f32x4*)src;
    f32x4 w1 = *(const f32x4*)(src + 4);
    bf16x8 f;
    f[0] = (__bf16)w0[0]; f[1] = (__bf16)w0[1];
    f[2] = (__bf16)w0[2]; f[3] = (__bf16)w0[3];
    f[4] = (__bf16)w1[0]; f[5] = (__bf16)w1[1];
    f[6] = (__bf16)w1[2]; f[7] = (__bf16)w1[3];
    wlds[g] = f;
  }
  __syncthreads();

  float bias[8];
#pragma unroll
  for (int k0 = 0; k0 < 8; ++k0) bias[k0] = bias_p[k0 * 16 + lr];

  const int wid = blockIdx.x * 4 + wave;
  const int nw = gridDim.x * 4;
  for (int seg = wid; seg < N_SEG; seg += nw) {
    const int base = (int)off[seg];
    const int c = (int)off[seg + 1] - base;

    float colsum[8] = {0.f, 0.f, 0.f, 0.f, 0.f, 0.f, 0.f, 0.f};

    for (int j = 0; j < c; j += 16) {
      const int ii = j + lr;
      const unsigned row = order[base + (ii < c ? ii : c - 1)];
      const float* erow = e + (size_t)row * DIM + lg * 8;

      bf16x8 afrag[4];
#pragma unroll
      for (int t = 0; t < 4; ++t) {
        f32x4 a0 = *(const f32x4*)(erow + t * 32);
        f32x4 a1 = *(const f32x4*)(erow + t * 32 + 4);
        bf16x8 f;
        f[0] = (__bf16)a0[0]; f[1] = (__bf16)a0[1];
        f[2] = (__bf16)a0[2]; f[3] = (__bf16)a0[3];
        f[4] = (__bf16)a1[0]; f[5] = (__bf16)a1[1];
        f[6] = (__bf16)a1[2]; f[7] = (__bf16)a1[3];
        afrag[t] = f;
      }

      f32x4 acc[8];
#pragma unroll
      for (int k0 = 0; k0 < 8; ++k0) acc[k0] = (f32x4){0.f, 0.f, 0.f, 0.f};
#pragma unroll
      for (int t = 0; t < 4; ++t) {
#pragma unroll
        for (int k0 = 0; k0 < 8; ++k0) {
          bf16x8 bf = wlds[(k0 * 4 + t) * 64 + lane];
          acc[k0] = __builtin_amdgcn_mfma_f32_16x16x32_bf16(afrag[t], bf,
                                                            acc[k0], 0, 0, 0);
        }
      }

      // bias + ReLU + masked row-sum into running column sums
#pragma unroll
      for (int r = 0; r < 4; ++r) {
        const bool valid = (j + lg * 4 + r) < c;
#pragma unroll
        for (int k0 = 0; k0 < 8; ++k0) {
          const float v = fmaxf(acc[k0][r] + bias[k0], 0.f);
          colsum[k0] += valid ? v : 0.f;
        }
      }
    }

    // reduce over the 4 lg groups; lanes 0..15 hold the 128 column sums
#pragma unroll
    for (int k0 = 0; k0 < 8; ++k0) {
      float s = colsum[k0];
      s += __shfl_xor(s, 16);
      s += __shfl_xor(s, 32);
      colsum[k0] = s;
    }
    if (lg == 0) {
      float* orow = out + (size_t)seg * DIM + lr;
#pragma unroll
      for (int k0 = 0; k0 < 8; ++k0) orow[k0 * 16] = colsum[k0];
    }
  }
}

extern "C" void kernel_launch(void* const* d_in, const int* in_sizes, int n_in,
                              void* d_out, int out_size, void* d_ws, size_t ws_size,
                              hipStream_t stream) {
  const float* e = (const float*)d_in[0];
  const int* idx = (const int*)d_in[1];
  const float* W = (const float*)d_in[2];
  const float* b = (const float*)d_in[3];
  float* out = (float*)d_out;
  unsigned* ws32 = (unsigned*)d_ws;

  const int n_e = in_sizes[0] / DIM;  // 1,600,000 rows

  // zero flag + histogram region (run/order are fully rewritten each call)
  hipMemsetAsync(d_ws, 0, (size_t)WS_RUN * sizeof(unsigned), stream);

  idx_probe_kernel<<<256, 256, 0, stream>>>((const unsigned*)idx, ws32,
                                            n_e / 2);
  hist_kernel<<<1024, 256, 0, stream>>>(idx, ws32, ws32 + WS_OFF, n_e);
  scan_kernel<<<1, 1024, 0, stream>>>(ws32 + WS_OFF, ws32 + WS_RUN);
  rank_kernel<<<1024, 256, 0, stream>>>(idx, ws32, ws32 + WS_RUN,
                                        ws32 + WS_ORDER, n_e);
  fused_main<<<4096, 256, 0, stream>>>(e, W, b, ws32 + WS_OFF, ws32 + WS_ORDER,
                                       out);
}

// Round 4
// 771.597 us; speedup vs baseline: 1.8584x; 1.8584x over previous
//
#include <hip/hip_runtime.h>
#include <hip/hip_bf16.h>

#define DIM 128
#define N_SEG 100000
#define N_TOT (N_SEG + 1)  // offsets array length
#define NB 98              // ceil(N_TOT / 1024)

typedef __attribute__((ext_vector_type(8))) __bf16 bf16x8;
typedef __attribute__((ext_vector_type(4))) float f32x4;

// ---- d_ws layout (u32 element offsets) -------------------------------------
#define WS_FLAG 0
#define WS_OFF 64                    // off[N_TOT]: counts -> exclusive offsets
#define WS_RUN (WS_OFF + N_TOT + 1)  // run[N_SEG]: rank-scatter cursors
#define WS_BSUM (WS_RUN + N_SEG)     // bsum[128]
#define WS_BPRE (WS_BSUM + 128)      // bpre[128]
#define WS_ORDER (WS_BPRE + 128)     // order[1.6M]
// total ~= 1,800,400 u32 = 7.2 MB

// ---------------------------------------------------------------------------
// Probe: int64 index => every odd 32-bit word is 0. flag=1 => int32 layout.
// ---------------------------------------------------------------------------
__global__ void idx_probe_kernel(const unsigned* __restrict__ idx32,
                                 unsigned* __restrict__ flag, int n) {
  unsigned v = 0;
  const int stride = gridDim.x * blockDim.x;
  for (int i = blockIdx.x * blockDim.x + threadIdx.x; i < n; i += stride)
    v |= idx32[2 * i + 1];
  if (v) atomicOr(flag, 1u);
}

__global__ void hist_kernel(const int* __restrict__ idx,
                            const unsigned* __restrict__ flag,
                            unsigned* __restrict__ cnt, int n) {
  const bool idx64 = (*flag == 0u);
  const int stride = gridDim.x * blockDim.x;
  for (int i = blockIdx.x * blockDim.x + threadIdx.x; i < n; i += stride) {
    const int v = idx64 ? idx[2 * i] : idx[i];
    atomicAdd(&cnt[v], 1u);
  }
}

// ---- coalesced 3-phase exclusive scan over off[N_TOT] -----------------------
__global__ __launch_bounds__(1024) void scan_bsum(const unsigned* __restrict__ off,
                                                  unsigned* __restrict__ bsum) {
  __shared__ unsigned ws[16];
  const int t = threadIdx.x;
  const int i = blockIdx.x * 1024 + t;
  unsigned v = (i < N_TOT) ? off[i] : 0u;
#pragma unroll
  for (int d = 1; d < 64; d <<= 1) v += __shfl_xor(v, d);
  if ((t & 63) == 0) ws[t >> 6] = v;
  __syncthreads();
  if (t == 0) {
    unsigned s = 0;
#pragma unroll
    for (int w = 0; w < 16; ++w) s += ws[w];
    bsum[blockIdx.x] = s;
  }
}

__global__ __launch_bounds__(128) void scan_btop(unsigned* __restrict__ bsum,
                                                 unsigned* __restrict__ bpre) {
  __shared__ unsigned part[128];
  const int t = threadIdx.x;
  unsigned v = (t < NB) ? bsum[t] : 0u;
  part[t] = v;
  __syncthreads();
  for (int d = 1; d < 128; d <<= 1) {
    const unsigned u = (t >= d) ? part[t - d] : 0u;
    __syncthreads();
    part[t] += u;
    __syncthreads();
  }
  bpre[t] = part[t] - v;  // exclusive
}

__global__ __launch_bounds__(1024) void scan_fixup(unsigned* __restrict__ off,
                                                   unsigned* __restrict__ run,
                                                   const unsigned* __restrict__ bpre) {
  __shared__ unsigned wsum[16], wpre[16];
  const int t = threadIdx.x;
  const int lane = t & 63;
  const int wv = t >> 6;
  const int i = blockIdx.x * 1024 + t;
  const unsigned v = (i < N_TOT) ? off[i] : 0u;
  unsigned s = v;
#pragma unroll
  for (int d = 1; d < 64; d <<= 1) {
    const unsigned u = __shfl_up(s, d);
    if (lane >= d) s += u;
  }
  if (lane == 63) wsum[wv] = s;
  __syncthreads();
  if (t < 16) {
    unsigned w = wsum[t];
    unsigned ps = w;
#pragma unroll
    for (int d = 1; d < 16; d <<= 1) {
      const unsigned u = __shfl_up(ps, d, 16);
      if (t >= d) ps += u;
    }
    wpre[t] = ps - w;  // exclusive across waves
  }
  __syncthreads();
  const unsigned excl = (s - v) + wpre[wv] + bpre[blockIdx.x];
  if (i < N_TOT) off[i] = excl;
  if (i < N_SEG) run[i] = excl;
}

__global__ void rank_kernel(const int* __restrict__ idx,
                            const unsigned* __restrict__ flag,
                            unsigned* __restrict__ run,
                            unsigned* __restrict__ order, int n) {
  const bool idx64 = (*flag == 0u);
  const int stride = gridDim.x * blockDim.x;
  for (int i = blockIdx.x * blockDim.x + threadIdx.x; i < n; i += stride) {
    const int v = idx64 ? idx[2 * i] : idx[i];
    const unsigned pos = atomicAdd(&run[v], 1u);
    order[pos] = (unsigned)i;
  }
}

// ---------------------------------------------------------------------------
// Main: one wave per segment, gather 16-row chunks via order[], MFMA against
// LDS-resident W fragments, masked bias+ReLU fold into register column sums,
// cross-lane reduce, one plain store per out row. Zero atomics.
// Register diet: N-tiles processed in 2 halves so peak live set is
// afrag(16) + acc(16) + colsum(8) + bias(8) ~= 70 VGPR incl. addressing.
//
// Fragment layouts (mfma_f32_16x16x32_bf16, m89-verified):
//   A (lane l, elem j): e[row_{l&15}][32t + (l>>4)*8 + j]
//   B (lane l, elem j): W[k0*16 + (l&15)][32t + (l>>4)*8 + j]   (LDS frags)
//   C/D (lane l, reg r): h[chunk row (l>>4)*4 + r][k0*16 + (l&15)]
// ---------------------------------------------------------------------------
__global__ __launch_bounds__(256, 3) void fused_main(
    const float* __restrict__ e, const float* __restrict__ W,
    const float* __restrict__ bias_p, const unsigned* __restrict__ off,
    const unsigned* __restrict__ order, float* __restrict__ out) {
  __shared__ bf16x8 wlds[2048];  // 32 KiB: [k0][t][lane] fragment-major

  const int tid = threadIdx.x;
  const int wave = tid >> 6;
  const int lane = tid & 63;
  const int lr = lane & 15;
  const int lg = lane >> 4;

  // one-time: stage W as bf16 fragments into LDS
#pragma unroll
  for (int j = 0; j < 8; ++j) {
    const int g = (tid << 3) | j;
    const int gl = g & 63;
    const int tt = (g >> 6) & 3;
    const int k0 = g >> 8;
    const int row = k0 * 16 + (gl & 15);
    const int col = tt * 32 + (gl >> 4) * 8;
    const float* src = W + (size_t)row * DIM + col;
    f32x4 w0 = *(const f32x4*)src;
    f32x4 w1 = *(const f32x4*)(src + 4);
    bf16x8 f;
    f[0] = (__bf16)w0[0]; f[1] = (__bf16)w0[1];
    f[2] = (__bf16)w0[2]; f[3] = (__bf16)w0[3];
    f[4] = (__bf16)w1[0]; f[5] = (__bf16)w1[1];
    f[6] = (__bf16)w1[2]; f[7] = (__bf16)w1[3];
    wlds[g] = f;
  }
  __syncthreads();

  float bias[8];
#pragma unroll
  for (int k0 = 0; k0 < 8; ++k0) bias[k0] = bias_p[k0 * 16 + lr];

  const int wid = blockIdx.x * 4 + wave;
  const int nw = gridDim.x * 4;
  for (int seg = wid; seg < N_SEG; seg += nw) {
    const int base = (int)off[seg];
    const int c = (int)off[seg + 1] - base;

    float colsum[8] = {0.f, 0.f, 0.f, 0.f, 0.f, 0.f, 0.f, 0.f};

    for (int j = 0; j < c; j += 16) {
      const int ii = j + lr;
      const unsigned row = order[base + (ii < c ? ii : c - 1)];
      const float* erow = e + (size_t)row * DIM + lg * 8;

      bf16x8 afrag[4];
#pragma unroll
      for (int t = 0; t < 4; ++t) {
        f32x4 a0 = *(const f32x4*)(erow + t * 32);
        f32x4 a1 = *(const f32x4*)(erow + t * 32 + 4);
        bf16x8 f;
        f[0] = (__bf16)a0[0]; f[1] = (__bf16)a0[1];
        f[2] = (__bf16)a0[2]; f[3] = (__bf16)a0[3];
        f[4] = (__bf16)a1[0]; f[5] = (__bf16)a1[1];
        f[6] = (__bf16)a1[2]; f[7] = (__bf16)a1[3];
        afrag[t] = f;
      }

#pragma unroll
      for (int half = 0; half < 2; ++half) {
        f32x4 acc[4];
#pragma unroll
        for (int k = 0; k < 4; ++k) acc[k] = (f32x4){0.f, 0.f, 0.f, 0.f};
#pragma unroll
        for (int t = 0; t < 4; ++t) {
#pragma unroll
          for (int k = 0; k < 4; ++k) {
            bf16x8 bf = wlds[((half * 4 + k) * 4 + t) * 64 + lane];
            acc[k] = __builtin_amdgcn_mfma_f32_16x16x32_bf16(afrag[t], bf,
                                                             acc[k], 0, 0, 0);
          }
        }
#pragma unroll
        for (int r = 0; r < 4; ++r) {
          const bool valid = (j + lg * 4 + r) < c;
#pragma unroll
          for (int k = 0; k < 4; ++k) {
            const float v = fmaxf(acc[k][r] + bias[half * 4 + k], 0.f);
            colsum[half * 4 + k] += valid ? v : 0.f;
          }
        }
      }
    }

    // reduce over the 4 lg groups; lanes 0..15 hold the 128 column sums
#pragma unroll
    for (int k0 = 0; k0 < 8; ++k0) {
      float s = colsum[k0];
      s += __shfl_xor(s, 16);
      s += __shfl_xor(s, 32);
      colsum[k0] = s;
    }
    if (lg == 0) {
      float* orow = out + (size_t)seg * DIM + lr;
#pragma unroll
      for (int k0 = 0; k0 < 8; ++k0) orow[k0 * 16] = colsum[k0];
    }
  }
}

extern "C" void kernel_launch(void* const* d_in, const int* in_sizes, int n_in,
                              void* d_out, int out_size, void* d_ws, size_t ws_size,
                              hipStream_t stream) {
  const float* e = (const float*)d_in[0];
  const int* idx = (const int*)d_in[1];
  const float* W = (const float*)d_in[2];
  const float* b = (const float*)d_in[3];
  float* out = (float*)d_out;
  unsigned* ws32 = (unsigned*)d_ws;

  const int n_e = in_sizes[0] / DIM;  // 1,600,000 rows

  // zero flag + histogram region (everything else is fully rewritten per call)
  hipMemsetAsync(d_ws, 0, (size_t)WS_RUN * sizeof(unsigned), stream);

  idx_probe_kernel<<<64, 256, 0, stream>>>((const unsigned*)idx, ws32,
                                           n_e / 2);
  hist_kernel<<<1024, 256, 0, stream>>>(idx, ws32, ws32 + WS_OFF, n_e);
  scan_bsum<<<NB, 1024, 0, stream>>>(ws32 + WS_OFF, ws32 + WS_BSUM);
  scan_btop<<<1, 128, 0, stream>>>(ws32 + WS_BSUM, ws32 + WS_BPRE);
  scan_fixup<<<NB, 1024, 0, stream>>>(ws32 + WS_OFF, ws32 + WS_RUN,
                                      ws32 + WS_BPRE);
  rank_kernel<<<1024, 256, 0, stream>>>(idx, ws32, ws32 + WS_RUN,
                                        ws32 + WS_ORDER, n_e);
  fused_main<<<2048, 256, 0, stream>>>(e, W, b, ws32 + WS_OFF, ws32 + WS_ORDER,
                                       out);
}

// Round 5
// 547.280 us; speedup vs baseline: 2.6201x; 1.4099x over previous
//
#include <hip/hip_runtime.h>
#include <hip/hip_bf16.h>

#define DIM 128
#define N_SEG 100000
#define N_TOT (N_SEG + 1)  // offsets array length
#define NB 98              // ceil(N_TOT / 1024)

typedef __attribute__((ext_vector_type(8))) __bf16 bf16x8;
typedef __attribute__((ext_vector_type(4))) float f32x4;

// ---- d_ws layout (u32 element offsets) -------------------------------------
// [0] flag (idx width probe)   [1] ucnt (number of work units)
#define WS_OFF 64                    // off[N_TOT]: counts -> exclusive offsets
#define WS_RUN (WS_OFF + N_TOT + 1)  // run[N_SEG]: rank-scatter cursors
#define WS_BSUM (WS_RUN + N_SEG)     // bsum[128]
#define WS_BPRE (WS_BSUM + 128)      // bpre[128]
#define WS_UNITS (WS_BPRE + 128)     // uint2 units[200K] (400K u32, 8B-aligned)
#define WS_ORDER (WS_UNITS + 400000) // order[1.6M]
// total ~= 2.2M u32 = 8.8 MB

// ---------------------------------------------------------------------------
// Probe: int64 index => every odd 32-bit word is 0. flag=1 => int32 layout.
// ---------------------------------------------------------------------------
__global__ void idx_probe_kernel(const unsigned* __restrict__ idx32,
                                 unsigned* __restrict__ flag, int n) {
  unsigned v = 0;
  const int stride = gridDim.x * blockDim.x;
  for (int i = blockIdx.x * blockDim.x + threadIdx.x; i < n; i += stride)
    v |= idx32[2 * i + 1];
  if (v) atomicOr(flag, 1u);
}

__global__ void hist_kernel(const int* __restrict__ idx,
                            const unsigned* __restrict__ flag,
                            unsigned* __restrict__ cnt, int n) {
  const bool idx64 = (*flag == 0u);
  const int stride = gridDim.x * blockDim.x;
  for (int i = blockIdx.x * blockDim.x + threadIdx.x; i < n; i += stride) {
    const int v = idx64 ? idx[2 * i] : idx[i];
    atomicAdd(&cnt[v], 1u);
  }
}

// ---- coalesced 3-phase exclusive scan over off[N_TOT] -----------------------
__global__ __launch_bounds__(1024) void scan_bsum(const unsigned* __restrict__ off,
                                                  unsigned* __restrict__ bsum) {
  __shared__ unsigned ws[16];
  const int t = threadIdx.x;
  const int i = blockIdx.x * 1024 + t;
  unsigned v = (i < N_TOT) ? off[i] : 0u;
#pragma unroll
  for (int d = 1; d < 64; d <<= 1) v += __shfl_xor(v, d);
  if ((t & 63) == 0) ws[t >> 6] = v;
  __syncthreads();
  if (t == 0) {
    unsigned s = 0;
#pragma unroll
    for (int w = 0; w < 16; ++w) s += ws[w];
    bsum[blockIdx.x] = s;
  }
}

__global__ __launch_bounds__(128) void scan_btop(unsigned* __restrict__ bsum,
                                                 unsigned* __restrict__ bpre) {
  __shared__ unsigned part[128];
  const int t = threadIdx.x;
  unsigned v = (t < NB) ? bsum[t] : 0u;
  part[t] = v;
  __syncthreads();
  for (int d = 1; d < 128; d <<= 1) {
    const unsigned u = (t >= d) ? part[t - d] : 0u;
    __syncthreads();
    part[t] += u;
    __syncthreads();
  }
  bpre[t] = part[t] - v;  // exclusive
}

__global__ __launch_bounds__(1024) void scan_fixup(unsigned* __restrict__ off,
                                                   unsigned* __restrict__ run,
                                                   const unsigned* __restrict__ bpre) {
  __shared__ unsigned wsum[16], wpre[16];
  const int t = threadIdx.x;
  const int lane = t & 63;
  const int wv = t >> 6;
  const int i = blockIdx.x * 1024 + t;
  const unsigned v = (i < N_TOT) ? off[i] : 0u;
  unsigned s = v;
#pragma unroll
  for (int d = 1; d < 64; d <<= 1) {
    const unsigned u = __shfl_up(s, d);
    if (lane >= d) s += u;
  }
  if (lane == 63) wsum[wv] = s;
  __syncthreads();
  if (t < 16) {
    unsigned w = wsum[t];
    unsigned ps = w;
#pragma unroll
    for (int d = 1; d < 16; d <<= 1) {
      const unsigned u = __shfl_up(ps, d, 16);
      if (t >= d) ps += u;
    }
    wpre[t] = ps - w;  // exclusive across waves
  }
  __syncthreads();
  const unsigned excl = (s - v) + wpre[wv] + bpre[blockIdx.x];
  if (i < N_TOT) off[i] = excl;
  if (i < N_SEG) run[i] = excl;
}

__global__ void rank_kernel(const int* __restrict__ idx,
                            const unsigned* __restrict__ flag,
                            unsigned* __restrict__ run,
                            unsigned* __restrict__ order, int n) {
  const bool idx64 = (*flag == 0u);
  const int stride = gridDim.x * blockDim.x;
  for (int i = blockIdx.x * blockDim.x + threadIdx.x; i < n; i += stride) {
    const int v = idx64 ? idx[2 * i] : idx[i];
    const unsigned pos = atomicAdd(&run[v], 1u);
    order[pos] = (unsigned)i;
  }
}

// ---------------------------------------------------------------------------
// Build flattened work units: each covers <=32 rows of one segment.
// entry.x = start offset into order[]; entry.y = seg(17b) | (cnt-1)<<17 | solo<<23
// ---------------------------------------------------------------------------
__global__ void unit_build(const unsigned* __restrict__ off,
                           uint2* __restrict__ units,
                           unsigned* __restrict__ ucnt) {
  const int s = blockIdx.x * blockDim.x + threadIdx.x;
  if (s >= N_SEG) return;
  const unsigned b = off[s];
  const unsigned c = off[s + 1] - b;
  if (c == 0) return;
  const unsigned nu = (c + 31) >> 5;
  const unsigned pos = atomicAdd(ucnt, nu);
  const unsigned solo = (nu == 1) ? (1u << 23) : 0u;
  for (unsigned t = 0; t < nu; ++t) {
    const unsigned cnt = min(32u, c - 32u * t);
    uint2 ent;
    ent.x = b + 32u * t;
    ent.y = (unsigned)s | ((cnt - 1u) << 17) | solo;
    units[pos + t] = ent;
  }
}

// ---------------------------------------------------------------------------
// Main: one wave per unit (<=32 rows of one segment). Gather rows via
// order[], h = relu(e@W^T + b) via MFMA against LDS-resident W fragments,
// masked fold into register column sums, cross-lane reduce, then ONE
// store (solo) or atomic-add (rare multi-unit segment) per out row.
//
// Fragment layouts (mfma_f32_16x16x32_bf16, m89-verified):
//   A (lane l, elem j): e[row_{l&15}][32t + (l>>4)*8 + j]
//   B (lane l, elem j): W[k0*16 + (l&15)][32t + (l>>4)*8 + j]   (LDS frags)
//   C/D (lane l, reg r): h[tile row (l>>4)*4 + r][k0*16 + (l&15)]
// ---------------------------------------------------------------------------
__global__ __launch_bounds__(256, 2) void fused_main(
    const float* __restrict__ e, const float* __restrict__ W,
    const float* __restrict__ bias_p, const unsigned* __restrict__ order,
    const uint2* __restrict__ units, const unsigned* __restrict__ ucnt,
    float* __restrict__ out) {
  __shared__ bf16x8 wlds[2048];  // 32 KiB: [k0][t][lane] fragment-major

  const int tid = threadIdx.x;
  const int wave = tid >> 6;
  const int lane = tid & 63;
  const int lr = lane & 15;
  const int lg = lane >> 4;

  // one-time: stage W as bf16 fragments into LDS
#pragma unroll
  for (int j = 0; j < 8; ++j) {
    const int g = (tid << 3) | j;
    const int gl = g & 63;
    const int tt = (g >> 6) & 3;
    const int k0 = g >> 8;
    const int row = k0 * 16 + (gl & 15);
    const int col = tt * 32 + (gl >> 4) * 8;
    const float* src = W + (size_t)row * DIM + col;
    f32x4 w0 = *(const f32x4*)src;
    f32x4 w1 = *(const f32x4*)(src + 4);
    bf16x8 f;
    f[0] = (__bf16)w0[0]; f[1] = (__bf16)w0[1];
    f[2] = (__bf16)w0[2]; f[3] = (__bf16)w0[3];
    f[4] = (__bf16)w1[0]; f[5] = (__bf16)w1[1];
    f[6] = (__bf16)w1[2]; f[7] = (__bf16)w1[3];
    wlds[g] = f;
  }
  __syncthreads();

  float bias[8];
#pragma unroll
  for (int k0 = 0; k0 < 8; ++k0) bias[k0] = bias_p[k0 * 16 + lr];

  const int n_units = (int)*ucnt;
  const int wid = blockIdx.x * 4 + wave;
  const int nw = gridDim.x * 4;
  for (int u = wid; u < n_units; u += nw) {
    const uint2 ent = units[u];
    const int base = (int)ent.x;
    const int seg = (int)(ent.y & 0x1FFFFu);
    const int cnt = (int)((ent.y >> 17) & 63u) + 1;
    const bool solo = (ent.y >> 23) & 1u;

    float colsum[8] = {0.f, 0.f, 0.f, 0.f, 0.f, 0.f, 0.f, 0.f};

    const int ntile = (cnt + 15) >> 4;
    for (int t0 = 0; t0 < ntile; ++t0) {
      const int ii = t0 * 16 + lr;
      const unsigned row = order[base + (ii < cnt ? ii : cnt - 1)];
      const float* erow = e + (size_t)row * DIM + lg * 8;

      bf16x8 afrag[4];
#pragma unroll
      for (int t = 0; t < 4; ++t) {
        f32x4 a0 = *(const f32x4*)(erow + t * 32);
        f32x4 a1 = *(const f32x4*)(erow + t * 32 + 4);
        bf16x8 f;
        f[0] = (__bf16)a0[0]; f[1] = (__bf16)a0[1];
        f[2] = (__bf16)a0[2]; f[3] = (__bf16)a0[3];
        f[4] = (__bf16)a1[0]; f[5] = (__bf16)a1[1];
        f[6] = (__bf16)a1[2]; f[7] = (__bf16)a1[3];
        afrag[t] = f;
      }

      f32x4 acc[8];
#pragma unroll
      for (int k0 = 0; k0 < 8; ++k0) acc[k0] = (f32x4){0.f, 0.f, 0.f, 0.f};
#pragma unroll
      for (int t = 0; t < 4; ++t) {
#pragma unroll
        for (int k0 = 0; k0 < 8; ++k0) {
          bf16x8 bf = wlds[(k0 * 4 + t) * 64 + lane];
          acc[k0] = __builtin_amdgcn_mfma_f32_16x16x32_bf16(afrag[t], bf,
                                                            acc[k0], 0, 0, 0);
        }
      }

      // bias + ReLU + masked fold into running column sums
#pragma unroll
      for (int r = 0; r < 4; ++r) {
        const bool valid = (t0 * 16 + lg * 4 + r) < cnt;
#pragma unroll
        for (int k0 = 0; k0 < 8; ++k0) {
          const float v = fmaxf(acc[k0][r] + bias[k0], 0.f);
          colsum[k0] += valid ? v : 0.f;
        }
      }
    }

    // reduce over the 4 lg groups; lanes 0..15 hold the 128 column sums
#pragma unroll
    for (int k0 = 0; k0 < 8; ++k0) {
      float s = colsum[k0];
      s += __shfl_xor(s, 16);
      s += __shfl_xor(s, 32);
      colsum[k0] = s;
    }
    if (lg == 0) {
      float* orow = out + (size_t)seg * DIM + lr;
      if (solo) {
#pragma unroll
        for (int k0 = 0; k0 < 8; ++k0) orow[k0 * 16] = colsum[k0];
      } else {
#pragma unroll
        for (int k0 = 0; k0 < 8; ++k0)
          unsafeAtomicAdd(orow + k0 * 16, colsum[k0]);
      }
    }
  }
}

extern "C" void kernel_launch(void* const* d_in, const int* in_sizes, int n_in,
                              void* d_out, int out_size, void* d_ws, size_t ws_size,
                              hipStream_t stream) {
  const float* e = (const float*)d_in[0];
  const int* idx = (const int*)d_in[1];
  const float* W = (const float*)d_in[2];
  const float* b = (const float*)d_in[3];
  float* out = (float*)d_out;
  unsigned* ws32 = (unsigned*)d_ws;

  const int n_e = in_sizes[0] / DIM;  // 1,600,000 rows

  // zero flag + ucnt + histogram region; out (empty segments + atomic base)
  hipMemsetAsync(d_ws, 0, (size_t)WS_RUN * sizeof(unsigned), stream);
  hipMemsetAsync(d_out, 0, (size_t)out_size * sizeof(float), stream);

  idx_probe_kernel<<<64, 256, 0, stream>>>((const unsigned*)idx, ws32,
                                           n_e / 2);
  hist_kernel<<<1024, 256, 0, stream>>>(idx, ws32, ws32 + WS_OFF, n_e);
  scan_bsum<<<NB, 1024, 0, stream>>>(ws32 + WS_OFF, ws32 + WS_BSUM);
  scan_btop<<<1, 128, 0, stream>>>(ws32 + WS_BSUM, ws32 + WS_BPRE);
  scan_fixup<<<NB, 1024, 0, stream>>>(ws32 + WS_OFF, ws32 + WS_RUN,
                                      ws32 + WS_BPRE);
  rank_kernel<<<1024, 256, 0, stream>>>(idx, ws32, ws32 + WS_RUN,
                                        ws32 + WS_ORDER, n_e);
  unit_build<<<(N_SEG + 255) / 256, 256, 0, stream>>>(
      ws32 + WS_OFF, (uint2*)(ws32 + WS_UNITS), ws32 + 1);
  fused_main<<<2048, 256, 0, stream>>>(e, W, b, ws32 + WS_ORDER,
                                       (const uint2*)(ws32 + WS_UNITS),
                                       ws32 + 1, out);
}